// Round 5
// baseline (96.122 us; speedup 1.0000x reference)
//
#include <hip/hip_runtime.h>

#define NG   1024
#define IMH  128
#define IMW  128
#define NPIX (IMH * IMW)

// ---------------------------------------------------------------------------
// Kernel 1: fused preprocess + stable depth sort (rank sort) + scatter.
// 16 blocks x 256 threads. Per block: (A) all 1024 sort keys cooperatively
// into LDS; (B) rank of this block's 64 gaussians, compare-loop split 4 ways
// across the 4 waves; (C) wave 0 fully preprocesses the block's 64 gaussians
// (projection, 2D cov, SH color, conservative cull radii) and scatters to the
// depth-sorted SoA slot.
// ---------------------------------------------------------------------------
__global__ __launch_bounds__(256) void k_prep(
    const float* __restrict__ means,
    const float* __restrict__ sh,
    const float* __restrict__ opac,
    const float* __restrict__ scales,
    const float* __restrict__ rots,
    const float* __restrict__ campos,
    const float* __restrict__ camrot,
    const float* __restrict__ thf_p,
    const float* __restrict__ nearfar,
    float4* __restrict__ g0, float4* __restrict__ g1, float4* __restrict__ g2)
{
    __shared__ unsigned long long lk[NG];
    __shared__ int prank[4 * 64];

    int t = threadIdx.x;
    int b = blockIdx.x;

    float thf = thf_p[0];
    float R[9];
    #pragma unroll
    for (int k = 0; k < 9; k++) R[k] = camrot[k];
    float cp0 = campos[0], cp1 = campos[1], cp2 = campos[2];
    float near_ = nearfar[0], far_ = nearfar[1];

    // --- stage A: all 1024 keys (4 per thread), stable (idx in low bits)
    #pragma unroll
    for (int j = 0; j < 4; j++) {
        int g = j * 256 + t;
        float dx = means[3 * g + 0] - cp0;
        float dy = means[3 * g + 1] - cp1;
        float dz = means[3 * g + 2] - cp2;
        float tzk = R[6] * dx + R[7] * dy + R[8] * dz;
        unsigned u = __float_as_uint(tzk);
        u = (u & 0x80000000u) ? ~u : (u | 0x80000000u);
        lk[g] = ((unsigned long long)u << 32) | (unsigned)g;
    }
    __syncthreads();

    // --- stage B: partial ranks; thread t handles gaussian b*64+(t&63),
    // compare-range chunk (t>>6)*256..+256
    int li    = t & 63;
    int chunk = t >> 6;
    int gi    = b * 64 + li;
    unsigned long long ki = lk[gi];
    int cnt = 0;
    int j0 = chunk * 256;
    #pragma unroll 8
    for (int j = 0; j < 256; j++) cnt += (lk[j0 + j] < ki) ? 1 : 0;
    prank[chunk * 64 + li] = cnt;
    __syncthreads();

    // --- stage C: full preprocess by wave 0 only (one gaussian per lane)
    if (t < 64) {
        int i = b * 64 + t;
        float fx = IMW / (2.0f * thf);
        float fy = IMH / (2.0f * thf);

        float d0x = means[3 * i + 0] - cp0;
        float d0y = means[3 * i + 1] - cp1;
        float d0z = means[3 * i + 2] - cp2;

        float tx0 = R[0] * d0x + R[1] * d0y + R[2] * d0z;
        float ty0 = R[3] * d0x + R[4] * d0y + R[5] * d0z;
        float tz  = R[6] * d0x + R[7] * d0y + R[8] * d0z;

        float lim  = 1.3f * thf;
        float invz = 1.0f / tz;
        float txc  = fminf(fmaxf(tx0 * invz, -lim), lim) * tz;
        float tyc  = fminf(fmaxf(ty0 * invz, -lim), lim) * tz;

        float qr = rots[4 * i + 0], qx = rots[4 * i + 1];
        float qy = rots[4 * i + 2], qz = rots[4 * i + 3];
        float qn = rsqrtf(qr * qr + qx * qx + qy * qy + qz * qz);
        qr *= qn; qx *= qn; qy *= qn; qz *= qn;
        float Rq0 = 1.0f - 2.0f * (qy * qy + qz * qz);
        float Rq1 = 2.0f * (qx * qy - qr * qz);
        float Rq2 = 2.0f * (qx * qz + qr * qy);
        float Rq3 = 2.0f * (qx * qy + qr * qz);
        float Rq4 = 1.0f - 2.0f * (qx * qx + qz * qz);
        float Rq5 = 2.0f * (qy * qz - qr * qx);
        float Rq6 = 2.0f * (qx * qz - qr * qy);
        float Rq7 = 2.0f * (qy * qz + qr * qx);
        float Rq8 = 1.0f - 2.0f * (qx * qx + qy * qy);

        float sx = scales[3 * i + 0], sy = scales[3 * i + 1], sz = scales[3 * i + 2];
        float M0 = Rq0 * sx, M1 = Rq1 * sy, M2 = Rq2 * sz;
        float M3 = Rq3 * sx, M4 = Rq4 * sy, M5 = Rq5 * sz;
        float M6 = Rq6 * sx, M7 = Rq7 * sy, M8 = Rq8 * sz;

        float c00 = M0 * M0 + M1 * M1 + M2 * M2;
        float c01 = M0 * M3 + M1 * M4 + M2 * M5;
        float c02 = M0 * M6 + M1 * M7 + M2 * M8;
        float c11 = M3 * M3 + M4 * M4 + M5 * M5;
        float c12 = M3 * M6 + M4 * M7 + M5 * M8;
        float c22 = M6 * M6 + M7 * M7 + M8 * M8;

        float z2  = tz * tz;
        float J00 = fx * invz, J02 = -fx * txc / z2;
        float J11 = fy * invz, J12 = -fy * tyc / z2;

        float T00 = J00 * R[0] + J02 * R[6];
        float T01 = J00 * R[1] + J02 * R[7];
        float T02 = J00 * R[2] + J02 * R[8];
        float T10 = J11 * R[3] + J12 * R[6];
        float T11 = J11 * R[4] + J12 * R[7];
        float T12 = J11 * R[5] + J12 * R[8];

        float v00 = T00 * c00 + T01 * c01 + T02 * c02;
        float v01 = T00 * c01 + T01 * c11 + T02 * c12;
        float v02 = T00 * c02 + T01 * c12 + T02 * c22;
        float v10 = T10 * c00 + T11 * c01 + T12 * c02;
        float v11 = T10 * c01 + T11 * c11 + T12 * c12;
        float v12 = T10 * c02 + T11 * c12 + T12 * c22;

        float a = v00 * T00 + v01 * T01 + v02 * T02 + 0.3f;
        float bb = v00 * T10 + v01 * T11 + v02 * T12;
        float c = v10 * T10 + v11 * T11 + v12 * T12 + 0.3f;

        float det    = a * c - bb * bb;
        float invdet = 1.0f / det;
        float conA = c * invdet, conB = -bb * invdet, conC = a * invdet;

        float mx = fx * tx0 * invz + (IMW - 1) * 0.5f;
        float my = fy * ty0 * invz + (IMH - 1) * 0.5f;

        // SH (degree 3)
        float dn = rsqrtf(d0x * d0x + d0y * d0y + d0z * d0z);
        float x = d0x * dn, y = d0y * dn, z = d0z * dn;
        float xx = x * x, yy = y * y, zz = z * z;
        float xy = x * y, yz = y * z, xz = x * z;

        float basis[16];
        basis[0]  = 0.28209479177387814f;
        basis[1]  = -0.4886025119029199f * y;
        basis[2]  =  0.4886025119029199f * z;
        basis[3]  = -0.4886025119029199f * x;
        basis[4]  =  1.0925484305920792f * xy;
        basis[5]  = -1.0925484305920792f * yz;
        basis[6]  =  0.31539156525252005f * (2.0f * zz - xx - yy);
        basis[7]  = -1.0925484305920792f * xz;
        basis[8]  =  0.5462742152960396f * (xx - yy);
        basis[9]  = -0.5900435899266435f * y * (3.0f * xx - yy);
        basis[10] =  2.890611442640554f * xy * z;
        basis[11] = -0.4570457994644658f * y * (4.0f * zz - xx - yy);
        basis[12] =  0.3731763325901154f * z * (2.0f * zz - 3.0f * xx - 3.0f * yy);
        basis[13] = -0.4570457994644658f * x * (4.0f * zz - xx - yy);
        basis[14] =  1.445305721320277f * z * (xx - yy);
        basis[15] = -0.5900435899266435f * x * (xx - 3.0f * yy);

        const float* shp = sh + i * 48;
        float col[3];
        #pragma unroll
        for (int ch = 0; ch < 3; ch++) {
            float res = 0.0f;
            #pragma unroll
            for (int k = 0; k < 16; k++) res += basis[k] * shp[k * 3 + ch];
            col[ch] = fmaxf(res + 0.5f, 0.0f);
        }

        bool valid = (tz > near_) && (tz < far_) && (det > 0.0f);
        float op = valid ? opac[i] : 0.0f;

        // conservative cull radii: alpha >= 1/255 requires
        // d^T Sigma'^-1 d <= s2 = 2 ln(255*op) -> |dx|<=sqrt(s2*a), |dy|<=sqrt(s2*c)
        float rx, ry;
        if (op >= (1.0f / 255.0f)) {
            float s2 = 2.0f * logf(255.0f * op);
            rx = sqrtf(s2 * a) + 1e-3f;
            ry = sqrtf(s2 * c) + 1e-3f;
        } else {
            rx = -1.0f; ry = -1.0f;   // never intersects any tile
        }

        int r = prank[0 * 64 + t] + prank[1 * 64 + t] +
                prank[2 * 64 + t] + prank[3 * 64 + t];

        g0[r] = make_float4(mx, my, rx, ry);
        g1[r] = make_float4(-0.5f * conA, -conB, -0.5f * conC, op);
        g2[r] = make_float4(col[0], col[1], col[2], 0.0f);
    }
}

// ---------------------------------------------------------------------------
// Kernel 2: tile compositing, ONE WAVE per 8x8 tile (256 blocks x 64 thr).
// The wave culls the sorted list in 16 rounds of 64 (ballot + order-
// preserving compaction into LDS; wave-synchronous, zero barriers), then
// lane = pixel walks the survivor list in depth order via broadcast LDS
// reads. No segment split, no reduction phase.
// ---------------------------------------------------------------------------
__global__ __launch_bounds__(64) void k_comp(
    const float4* __restrict__ g0, const float4* __restrict__ g1,
    const float4* __restrict__ g2, const float* __restrict__ bg,
    float* __restrict__ out)
{
    __shared__ float4 lA[NG];        // mx, my, A2, B2
    __shared__ float4 lB[NG];        // C2, op, col_r, col_g
    __shared__ float  lC[NG];        // col_b

    int lane = threadIdx.x;
    int bx = blockIdx.x & 15, by = blockIdx.x >> 4;
    float x0 = (float)(bx * 8), y0 = (float)(by * 8);

    // --- cull + order-preserving compaction (wave-synchronous)
    int base = 0;
    #pragma unroll 4
    for (int r = 0; r < 16; r++) {
        int gidx = r * 64 + lane;
        float4 c0 = g0[gidx];
        bool surv = (c0.z >= 0.0f) &&
                    (c0.x + c0.z >= x0) && (c0.x - c0.z <= x0 + 7.0f) &&
                    (c0.y + c0.w >= y0) && (c0.y - c0.w <= y0 + 7.0f);
        unsigned long long m = __ballot(surv);
        if (surv) {
            int pos = base + __popcll(m & ((1ull << lane) - 1ull));
            float4 c1 = g1[gidx];
            float4 c2 = g2[gidx];
            lA[pos] = make_float4(c0.x, c0.y, c1.x, c1.y);
            lB[pos] = make_float4(c1.z, c1.w, c2.x, c2.y);
            lC[pos] = c2.z;
        }
        base += __popcll(m);
    }
    int M = base;   // wave-uniform survivor count

    // --- composite: lane = pixel, full survivor list in depth order
    float fpx = x0 + (float)(lane & 7);
    float fpy = y0 + (float)(lane >> 3);
    float T = 1.0f, cr = 0.0f, cg = 0.0f, cb = 0.0f;

    #pragma unroll 2
    for (int k = 0; k < M; k++) {
        float4 qA = lA[k];          // broadcast LDS reads (same addr all lanes)
        float4 qB = lB[k];
        float  qc = lC[k];
        float dx = fpx - qA.x;
        float dy = fpy - qA.y;
        float pw = fmaf(dx, fmaf(qA.z, dx, qA.w * dy), qB.x * (dy * dy));
        float al = qB.y * __expf(pw);
        al = fminf(al, 0.99f);
        bool ok = (pw <= 0.0f) && (al >= (1.0f / 255.0f));
        al = ok ? al : 0.0f;
        float w = al * T;
        cr = fmaf(w, qB.z, cr);
        cg = fmaf(w, qB.w, cg);
        cb = fmaf(w, qc, cb);
        T = fmaf(-al, T, T);
    }

    int pix = (by * 8 + (lane >> 3)) * IMW + bx * 8 + (lane & 7);
    out[0 * NPIX + pix] = cr + T * bg[0];
    out[1 * NPIX + pix] = cg + T * bg[1];
    out[2 * NPIX + pix] = cb + T * bg[2];
}

// ---------------------------------------------------------------------------
extern "C" void kernel_launch(void* const* d_in, const int* in_sizes, int n_in,
                              void* d_out, int out_size, void* d_ws, size_t ws_size,
                              hipStream_t stream)
{
    (void)in_sizes; (void)n_in; (void)out_size; (void)ws_size;

    const float* means   = (const float*)d_in[0];
    const float* sh      = (const float*)d_in[1];
    const float* opac    = (const float*)d_in[2];
    const float* scales  = (const float*)d_in[3];
    const float* rots    = (const float*)d_in[4];
    const float* campos  = (const float*)d_in[5];
    const float* camrot  = (const float*)d_in[6];
    const float* thf     = (const float*)d_in[7];
    const float* bg      = (const float*)d_in[8];
    const float* nearfar = (const float*)d_in[9];

    char* ws = (char*)d_ws;
    float4* g0 = (float4*)(ws + 0);
    float4* g1 = (float4*)(ws + 16384);
    float4* g2 = (float4*)(ws + 32768);

    k_prep<<<16, 256, 0, stream>>>(means, sh, opac, scales, rots, campos,
                                   camrot, thf, nearfar, g0, g1, g2);
    k_comp<<<256, 64, 0, stream>>>(g0, g1, g2, bg, (float*)d_out);
}

// Round 6
// 85.529 us; speedup vs baseline: 1.1239x; 1.1239x over previous
//
#include <hip/hip_runtime.h>

#define NG   1024
#define IMH  128
#define IMW  128
#define NPIX (IMH * IMW)
#define SEGS 16

// ---------------------------------------------------------------------------
// Kernel 1: fused preprocess + stable depth sort (rank sort) + scatter.
// 64 blocks x 256 threads; block b owns gaussians [b*16, b*16+16).
// (A) all 1024 sort keys cooperatively into LDS (4/thread);
// (B) rank of the block's 16 gaussians, compare loop split 16 ways
//     (thread = (gaussian, 64-key chunk), 64 compares each);
// (C) lanes 0..15 fully preprocess the 16 gaussians (float4 SH loads) and
//     scatter to the depth-sorted SoA slot.
// ---------------------------------------------------------------------------
__global__ __launch_bounds__(256) void k_prep(
    const float* __restrict__ means,
    const float* __restrict__ sh,
    const float* __restrict__ opac,
    const float* __restrict__ scales,
    const float* __restrict__ rots,
    const float* __restrict__ campos,
    const float* __restrict__ camrot,
    const float* __restrict__ thf_p,
    const float* __restrict__ nearfar,
    float4* __restrict__ g0, float4* __restrict__ g1, float4* __restrict__ g2)
{
    __shared__ unsigned long long lk[NG];
    __shared__ int prank[16][16];   // [chunk][gauss]

    int t = threadIdx.x;
    int b = blockIdx.x;

    float thf = thf_p[0];
    float R[9];
    #pragma unroll
    for (int k = 0; k < 9; k++) R[k] = camrot[k];
    float cp0 = campos[0], cp1 = campos[1], cp2 = campos[2];
    float near_ = nearfar[0], far_ = nearfar[1];

    // --- stage A: all 1024 keys (4 per thread), stable (idx in low bits)
    #pragma unroll
    for (int j = 0; j < 4; j++) {
        int g = j * 256 + t;
        float dx = means[3 * g + 0] - cp0;
        float dy = means[3 * g + 1] - cp1;
        float dz = means[3 * g + 2] - cp2;
        float tzk = R[6] * dx + R[7] * dy + R[8] * dz;
        unsigned u = __float_as_uint(tzk);
        u = (u & 0x80000000u) ? ~u : (u | 0x80000000u);
        lk[g] = ((unsigned long long)u << 32) | (unsigned)g;
    }
    __syncthreads();

    // --- stage B: partial ranks (gaussian = t&15, key chunk = t>>4)
    int gl    = t & 15;
    int chunk = t >> 4;
    unsigned long long ki = lk[b * 16 + gl];
    int cnt = 0;
    int j0 = chunk * 64;
    #pragma unroll 8
    for (int j = 0; j < 64; j++) cnt += (lk[j0 + j] < ki) ? 1 : 0;
    prank[chunk][gl] = cnt;
    __syncthreads();

    // --- stage C: full preprocess, one gaussian per lane (lanes 0..15)
    if (t < 16) {
        int i = b * 16 + t;
        float fx = IMW / (2.0f * thf);
        float fy = IMH / (2.0f * thf);

        int r = 0;
        #pragma unroll
        for (int c2i = 0; c2i < 16; c2i++) r += prank[c2i][t];

        float d0x = means[3 * i + 0] - cp0;
        float d0y = means[3 * i + 1] - cp1;
        float d0z = means[3 * i + 2] - cp2;

        float tx0 = R[0] * d0x + R[1] * d0y + R[2] * d0z;
        float ty0 = R[3] * d0x + R[4] * d0y + R[5] * d0z;
        float tz  = R[6] * d0x + R[7] * d0y + R[8] * d0z;

        float lim  = 1.3f * thf;
        float invz = 1.0f / tz;
        float txc  = fminf(fmaxf(tx0 * invz, -lim), lim) * tz;
        float tyc  = fminf(fmaxf(ty0 * invz, -lim), lim) * tz;

        float4 q = ((const float4*)rots)[i];
        float qr = q.x, qx = q.y, qy = q.z, qz = q.w;
        float qn = rsqrtf(qr * qr + qx * qx + qy * qy + qz * qz);
        qr *= qn; qx *= qn; qy *= qn; qz *= qn;
        float Rq0 = 1.0f - 2.0f * (qy * qy + qz * qz);
        float Rq1 = 2.0f * (qx * qy - qr * qz);
        float Rq2 = 2.0f * (qx * qz + qr * qy);
        float Rq3 = 2.0f * (qx * qy + qr * qz);
        float Rq4 = 1.0f - 2.0f * (qx * qx + qz * qz);
        float Rq5 = 2.0f * (qy * qz - qr * qx);
        float Rq6 = 2.0f * (qx * qz - qr * qy);
        float Rq7 = 2.0f * (qy * qz + qr * qx);
        float Rq8 = 1.0f - 2.0f * (qx * qx + qy * qy);

        float sx = scales[3 * i + 0], sy = scales[3 * i + 1], sz = scales[3 * i + 2];
        float M0 = Rq0 * sx, M1 = Rq1 * sy, M2 = Rq2 * sz;
        float M3 = Rq3 * sx, M4 = Rq4 * sy, M5 = Rq5 * sz;
        float M6 = Rq6 * sx, M7 = Rq7 * sy, M8 = Rq8 * sz;

        float c00 = M0 * M0 + M1 * M1 + M2 * M2;
        float c01 = M0 * M3 + M1 * M4 + M2 * M5;
        float c02 = M0 * M6 + M1 * M7 + M2 * M8;
        float c11 = M3 * M3 + M4 * M4 + M5 * M5;
        float c12 = M3 * M6 + M4 * M7 + M5 * M8;
        float c22 = M6 * M6 + M7 * M7 + M8 * M8;

        float z2  = tz * tz;
        float J00 = fx * invz, J02 = -fx * txc / z2;
        float J11 = fy * invz, J12 = -fy * tyc / z2;

        float T00 = J00 * R[0] + J02 * R[6];
        float T01 = J00 * R[1] + J02 * R[7];
        float T02 = J00 * R[2] + J02 * R[8];
        float T10 = J11 * R[3] + J12 * R[6];
        float T11 = J11 * R[4] + J12 * R[7];
        float T12 = J11 * R[5] + J12 * R[8];

        float v00 = T00 * c00 + T01 * c01 + T02 * c02;
        float v01 = T00 * c01 + T01 * c11 + T02 * c12;
        float v02 = T00 * c02 + T01 * c12 + T02 * c22;
        float v10 = T10 * c00 + T11 * c01 + T12 * c02;
        float v11 = T10 * c01 + T11 * c11 + T12 * c12;
        float v12 = T10 * c02 + T11 * c12 + T12 * c22;

        float a  = v00 * T00 + v01 * T01 + v02 * T02 + 0.3f;
        float bb = v00 * T10 + v01 * T11 + v02 * T12;
        float c  = v10 * T10 + v11 * T11 + v12 * T12 + 0.3f;

        float det    = a * c - bb * bb;
        float invdet = 1.0f / det;
        float conA = c * invdet, conB = -bb * invdet, conC = a * invdet;

        float mx = fx * tx0 * invz + (IMW - 1) * 0.5f;
        float my = fy * ty0 * invz + (IMH - 1) * 0.5f;

        // SH (degree 3) — 12 x float4 loads (sh + i*48 is 16B-aligned)
        float dn = rsqrtf(d0x * d0x + d0y * d0y + d0z * d0z);
        float x = d0x * dn, y = d0y * dn, z = d0z * dn;
        float xx = x * x, yy = y * y, zz = z * z;
        float xy = x * y, yz = y * z, xz = x * z;

        float basis[16];
        basis[0]  = 0.28209479177387814f;
        basis[1]  = -0.4886025119029199f * y;
        basis[2]  =  0.4886025119029199f * z;
        basis[3]  = -0.4886025119029199f * x;
        basis[4]  =  1.0925484305920792f * xy;
        basis[5]  = -1.0925484305920792f * yz;
        basis[6]  =  0.31539156525252005f * (2.0f * zz - xx - yy);
        basis[7]  = -1.0925484305920792f * xz;
        basis[8]  =  0.5462742152960396f * (xx - yy);
        basis[9]  = -0.5900435899266435f * y * (3.0f * xx - yy);
        basis[10] =  2.890611442640554f * xy * z;
        basis[11] = -0.4570457994644658f * y * (4.0f * zz - xx - yy);
        basis[12] =  0.3731763325901154f * z * (2.0f * zz - 3.0f * xx - 3.0f * yy);
        basis[13] = -0.4570457994644658f * x * (4.0f * zz - xx - yy);
        basis[14] =  1.445305721320277f * z * (xx - yy);
        basis[15] = -0.5900435899266435f * x * (xx - 3.0f * yy);

        float f[48];
        {
            const float4* sh4 = (const float4*)(sh + i * 48);
            float4* fv = (float4*)f;
            #pragma unroll
            for (int j = 0; j < 12; j++) fv[j] = sh4[j];
        }
        float colr = 0.0f, colg = 0.0f, colb = 0.0f;
        #pragma unroll
        for (int k = 0; k < 16; k++) {
            float bk = basis[k];
            colr = fmaf(bk, f[3 * k + 0], colr);
            colg = fmaf(bk, f[3 * k + 1], colg);
            colb = fmaf(bk, f[3 * k + 2], colb);
        }
        colr = fmaxf(colr + 0.5f, 0.0f);
        colg = fmaxf(colg + 0.5f, 0.0f);
        colb = fmaxf(colb + 0.5f, 0.0f);

        bool valid = (tz > near_) && (tz < far_) && (det > 0.0f);
        float op = valid ? opac[i] : 0.0f;

        // conservative cull radii: alpha >= 1/255 requires
        // d^T Sigma'^-1 d <= s2 = 2 ln(255*op) -> |dx|<=sqrt(s2*a), |dy|<=sqrt(s2*c)
        float rx, ry;
        if (op >= (1.0f / 255.0f)) {
            float s2 = 2.0f * logf(255.0f * op);
            rx = sqrtf(s2 * a) + 1e-3f;
            ry = sqrtf(s2 * c) + 1e-3f;
        } else {
            rx = -1.0f; ry = -1.0f;   // never intersects any tile
        }

        g0[r] = make_float4(mx, my, rx, ry);
        g1[r] = make_float4(-0.5f * conA, -conB, -0.5f * conC, op);
        g2[r] = make_float4(colr, colg, colb, 0.0f);
    }
}

// ---------------------------------------------------------------------------
// Kernel 2: tile compositing (R4 structure: 16 waves/block for latency
// hiding). Grid = 256 blocks (16x16 tiles of 8x8 px), block = 1024 threads.
// Phase 1: each thread AABB-culls one sorted gaussian (g1/g2 prefetched
// unconditionally); order-preserving ballot compaction into LDS.
// Phase 2: wave s composites survivor segment s for the tile's 64 pixels
// (lane = pixel) with wave-uniform broadcast LDS reads.
// Phase 3: ordered 16-segment combine in LDS, write out.
// ---------------------------------------------------------------------------
__global__ __launch_bounds__(1024) void k_comp(
    const float4* __restrict__ g0, const float4* __restrict__ g1,
    const float4* __restrict__ g2, const float* __restrict__ bg,
    float* __restrict__ out)
{
    __shared__ float4 lA[NG];        // mx, my, A2, B2
    __shared__ float4 lB[NG];        // C2, op, col_r, col_g
    __shared__ float  lC[NG];        // col_b
    __shared__ float4 red[SEGS * 64];
    __shared__ int wcnt[16];

    int t    = threadIdx.x;
    int wid  = t >> 6;
    int lane = t & 63;
    int bx = blockIdx.x & 15, by = blockIdx.x >> 4;
    float x0 = (float)(bx * 8), y0 = (float)(by * 8);

    // --- phase 1: cull + order-preserving compaction
    float4 c0 = g0[t];
    float4 c1 = g1[t];
    float4 c2 = g2[t];
    bool surv = (c0.z >= 0.0f) &&
                (c0.x + c0.z >= x0) && (c0.x - c0.z <= x0 + 7.0f) &&
                (c0.y + c0.w >= y0) && (c0.y - c0.w <= y0 + 7.0f);
    unsigned long long m = __ballot(surv);
    if (lane == 0) wcnt[wid] = __popcll(m);
    __syncthreads();

    int pre = 0, M = 0;
    #pragma unroll
    for (int w = 0; w < 16; w++) {
        int cw = wcnt[w];
        M += cw;
        if (w < wid) pre += cw;
    }
    if (surv) {
        int pos = pre + __popcll(m & ((1ull << lane) - 1ull));
        lA[pos] = make_float4(c0.x, c0.y, c1.x, c1.y);
        lB[pos] = make_float4(c1.z, c1.w, c2.x, c2.y);
        lC[pos] = c2.z;
    }
    __syncthreads();

    // --- phase 2: composite segment (wave-uniform bounds & addresses)
    M = __builtin_amdgcn_readfirstlane(M);
    int len = (M + SEGS - 1) / SEGS;
    int seg = __builtin_amdgcn_readfirstlane(wid);
    int ks  = seg * len;
    int ke  = min(M, ks + len);

    float fpx = x0 + (float)(lane & 7);
    float fpy = y0 + (float)(lane >> 3);

    float T = 1.0f, cr = 0.0f, cg = 0.0f, cb = 0.0f;
    for (int k = ks; k < ke; k++) {
        float4 qA = lA[k];
        float4 qB = lB[k];
        float  qc = lC[k];
        float dx = fpx - qA.x;
        float dy = fpy - qA.y;
        float pw = fmaf(dx, fmaf(qA.z, dx, qA.w * dy), qB.x * (dy * dy));
        float al = qB.y * __expf(pw);
        al = fminf(al, 0.99f);
        bool ok = (pw <= 0.0f) && (al >= (1.0f / 255.0f));
        al = ok ? al : 0.0f;
        float w = al * T;
        cr = fmaf(w, qB.z, cr);
        cg = fmaf(w, qB.w, cg);
        cb = fmaf(w, qc, cb);
        T = fmaf(-al, T, T);
    }

    red[seg * 64 + lane] = make_float4(cr, cg, cb, T);
    __syncthreads();

    // --- phase 3: ordered combine + store
    if (t < 64) {
        float Tt = 1.0f, r = 0.0f, g = 0.0f, b = 0.0f;
        #pragma unroll
        for (int s = 0; s < SEGS; s++) {
            float4 v = red[s * 64 + t];
            r = fmaf(Tt, v.x, r);
            g = fmaf(Tt, v.y, g);
            b = fmaf(Tt, v.z, b);
            Tt *= v.w;
        }
        int pix = (by * 8 + (t >> 3)) * IMW + bx * 8 + (t & 7);
        out[0 * NPIX + pix] = r + Tt * bg[0];
        out[1 * NPIX + pix] = g + Tt * bg[1];
        out[2 * NPIX + pix] = b + Tt * bg[2];
    }
}

// ---------------------------------------------------------------------------
extern "C" void kernel_launch(void* const* d_in, const int* in_sizes, int n_in,
                              void* d_out, int out_size, void* d_ws, size_t ws_size,
                              hipStream_t stream)
{
    (void)in_sizes; (void)n_in; (void)out_size; (void)ws_size;

    const float* means   = (const float*)d_in[0];
    const float* sh      = (const float*)d_in[1];
    const float* opac    = (const float*)d_in[2];
    const float* scales  = (const float*)d_in[3];
    const float* rots    = (const float*)d_in[4];
    const float* campos  = (const float*)d_in[5];
    const float* camrot  = (const float*)d_in[6];
    const float* thf     = (const float*)d_in[7];
    const float* bg      = (const float*)d_in[8];
    const float* nearfar = (const float*)d_in[9];

    char* ws = (char*)d_ws;
    float4* g0 = (float4*)(ws + 0);
    float4* g1 = (float4*)(ws + 16384);
    float4* g2 = (float4*)(ws + 32768);

    k_prep<<<64, 256, 0, stream>>>(means, sh, opac, scales, rots, campos,
                                   camrot, thf, nearfar, g0, g1, g2);
    k_comp<<<256, 1024, 0, stream>>>(g0, g1, g2, bg, (float*)d_out);
}

// Round 7
// 83.754 us; speedup vs baseline: 1.1477x; 1.0212x over previous
//
#include <hip/hip_runtime.h>

#define NG   1024
#define IMH  128
#define IMW  128
#define NPIX (IMH * IMW)
#define SEGS 16

// ---------------------------------------------------------------------------
// Single fused kernel: 256 blocks (one per 8x8 tile) x 1024 threads.
//
// Phase A: thread t preprocesses gaussian t IN REGISTERS (projection, 2D
//          cov, cull radii, validity-folded opacity). Redundant across
//          blocks, but only ~150 flops/thread — cheaper than a separate
//          kernel + launch gap + global round-trip.
// Phase B: AABB-cull vs this tile; order-preserving ballot compaction of
//          survivors (params + stable 64-bit depth key) into LDS.
// Phase C: survivors only (M ~ 21 avg): rank-sort by key (M compares each,
//          broadcast LDS reads), SH color eval, scatter into depth-sorted
//          LDS arrays.
// Phase D: wave s composites sorted survivor segment s for the tile's 64
//          pixels (lane = pixel), wave-uniform broadcast LDS reads.
// Phase E: ordered 16-segment combine, store.
//
// NOTE (R5 lesson): 1024-thread blocks keep 16 waves/CU resident; do NOT
// shrink the block below ~4 waves/SIMD — latency exposure dominates.
// ---------------------------------------------------------------------------
__global__ __launch_bounds__(1024) void k_fused(
    const float* __restrict__ means,
    const float* __restrict__ sh,
    const float* __restrict__ opac,
    const float* __restrict__ scales,
    const float* __restrict__ rots,
    const float* __restrict__ campos,
    const float* __restrict__ camrot,
    const float* __restrict__ thf_p,
    const float* __restrict__ nearfar,
    const float* __restrict__ bg,
    float* __restrict__ out)
{
    __shared__ float4 uA[NG];                 // unsorted: mx, my, A2, B2
    __shared__ float2 uB[NG];                 // unsorted: C2, op
    __shared__ unsigned long long ukey[NG];   // unsorted: (tz-bits << 32)|idx
    __shared__ float4 lA[NG];                 // sorted:   mx, my, A2, B2
    __shared__ float4 lB[NG];                 // sorted:   C2, op, col_r, col_g
    __shared__ float  lC[NG];                 // sorted:   col_b
    __shared__ float4 red[SEGS * 64];
    __shared__ int wcnt[16];

    int t    = threadIdx.x;
    int wid  = t >> 6;
    int lane = t & 63;
    int bx = blockIdx.x & 15, by = blockIdx.x >> 4;
    float x0 = (float)(bx * 8), y0 = (float)(by * 8);

    float thf = thf_p[0];
    float fx = IMW / (2.0f * thf);
    float fy = IMH / (2.0f * thf);
    float R[9];
    #pragma unroll
    for (int k = 0; k < 9; k++) R[k] = camrot[k];
    float cp0 = campos[0], cp1 = campos[1], cp2 = campos[2];
    float near_ = nearfar[0], far_ = nearfar[1];

    // ---------------- Phase A: preprocess gaussian t in registers ----------
    float d0x = means[3 * t + 0] - cp0;
    float d0y = means[3 * t + 1] - cp1;
    float d0z = means[3 * t + 2] - cp2;

    float tx0 = R[0] * d0x + R[1] * d0y + R[2] * d0z;
    float ty0 = R[3] * d0x + R[4] * d0y + R[5] * d0z;
    float tz  = R[6] * d0x + R[7] * d0y + R[8] * d0z;

    float lim  = 1.3f * thf;
    float invz = 1.0f / tz;
    float txc  = fminf(fmaxf(tx0 * invz, -lim), lim) * tz;
    float tyc  = fminf(fmaxf(ty0 * invz, -lim), lim) * tz;

    float4 q = ((const float4*)rots)[t];
    float qr = q.x, qx = q.y, qy = q.z, qz = q.w;
    float qn = rsqrtf(qr * qr + qx * qx + qy * qy + qz * qz);
    qr *= qn; qx *= qn; qy *= qn; qz *= qn;
    float Rq0 = 1.0f - 2.0f * (qy * qy + qz * qz);
    float Rq1 = 2.0f * (qx * qy - qr * qz);
    float Rq2 = 2.0f * (qx * qz + qr * qy);
    float Rq3 = 2.0f * (qx * qy + qr * qz);
    float Rq4 = 1.0f - 2.0f * (qx * qx + qz * qz);
    float Rq5 = 2.0f * (qy * qz - qr * qx);
    float Rq6 = 2.0f * (qx * qz - qr * qy);
    float Rq7 = 2.0f * (qy * qz + qr * qx);
    float Rq8 = 1.0f - 2.0f * (qx * qx + qy * qy);

    float sx = scales[3 * t + 0], sy = scales[3 * t + 1], sz = scales[3 * t + 2];
    float M0 = Rq0 * sx, M1 = Rq1 * sy, M2 = Rq2 * sz;
    float M3 = Rq3 * sx, M4 = Rq4 * sy, M5 = Rq5 * sz;
    float M6 = Rq6 * sx, M7 = Rq7 * sy, M8 = Rq8 * sz;

    float c00 = M0 * M0 + M1 * M1 + M2 * M2;
    float c01 = M0 * M3 + M1 * M4 + M2 * M5;
    float c02 = M0 * M6 + M1 * M7 + M2 * M8;
    float c11 = M3 * M3 + M4 * M4 + M5 * M5;
    float c12 = M3 * M6 + M4 * M7 + M5 * M8;
    float c22 = M6 * M6 + M7 * M7 + M8 * M8;

    float z2  = tz * tz;
    float J00 = fx * invz, J02 = -fx * txc / z2;
    float J11 = fy * invz, J12 = -fy * tyc / z2;

    float T00 = J00 * R[0] + J02 * R[6];
    float T01 = J00 * R[1] + J02 * R[7];
    float T02 = J00 * R[2] + J02 * R[8];
    float T10 = J11 * R[3] + J12 * R[6];
    float T11 = J11 * R[4] + J12 * R[7];
    float T12 = J11 * R[5] + J12 * R[8];

    float v00 = T00 * c00 + T01 * c01 + T02 * c02;
    float v01 = T00 * c01 + T01 * c11 + T02 * c12;
    float v02 = T00 * c02 + T01 * c12 + T02 * c22;
    float v10 = T10 * c00 + T11 * c01 + T12 * c02;
    float v11 = T10 * c01 + T11 * c11 + T12 * c12;
    float v12 = T10 * c02 + T11 * c12 + T12 * c22;

    float a  = v00 * T00 + v01 * T01 + v02 * T02 + 0.3f;
    float bb = v00 * T10 + v01 * T11 + v02 * T12;
    float c  = v10 * T10 + v11 * T11 + v12 * T12 + 0.3f;

    float det    = a * c - bb * bb;
    float invdet = 1.0f / det;
    float conA = c * invdet, conB = -bb * invdet, conC = a * invdet;

    float mx = fx * tx0 * invz + (IMW - 1) * 0.5f;
    float my = fy * ty0 * invz + (IMH - 1) * 0.5f;

    bool valid = (tz > near_) && (tz < far_) && (det > 0.0f);
    float op = valid ? opac[t] : 0.0f;

    // conservative cull radii (alpha >= 1/255 bound): |dx| <= sqrt(s2*a)
    float rx = -1.0f, ry = -1.0f;
    if (op >= (1.0f / 255.0f)) {
        float s2 = 2.0f * logf(255.0f * op);
        rx = sqrtf(s2 * a) + 1e-3f;
        ry = sqrtf(s2 * c) + 1e-3f;
    }

    // ---------------- Phase B: cull + ballot compaction (unsorted) ---------
    bool surv = (rx >= 0.0f) &&
                (mx + rx >= x0) && (mx - rx <= x0 + 7.0f) &&
                (my + ry >= y0) && (my - ry <= y0 + 7.0f);
    unsigned long long m = __ballot(surv);
    if (lane == 0) wcnt[wid] = __popcll(m);
    __syncthreads();

    int pre = 0, M = 0;
    #pragma unroll
    for (int w = 0; w < 16; w++) {
        int cw = wcnt[w];
        M += cw;
        if (w < wid) pre += cw;
    }
    if (surv) {
        int pos = pre + __popcll(m & ((1ull << lane) - 1ull));
        uA[pos] = make_float4(mx, my, -0.5f * conA, -conB);
        uB[pos] = make_float2(-0.5f * conC, op);
        unsigned u = __float_as_uint(tz);
        u = (u & 0x80000000u) ? ~u : (u | 0x80000000u);
        ukey[pos] = ((unsigned long long)u << 32) | (unsigned)t;
    }
    __syncthreads();

    // ---------------- Phase C: survivors only — rank-sort + SH + scatter ---
    if (t < M) {
        unsigned long long kt = ukey[t];
        int r = 0;
        for (int j = 0; j < M; j++) r += (ukey[j] < kt) ? 1 : 0;

        int idx = (int)(kt & 0xffffffffu);

        // SH (degree 3) for survivor idx
        float gx = means[3 * idx + 0] - cp0;
        float gy = means[3 * idx + 1] - cp1;
        float gz = means[3 * idx + 2] - cp2;
        float dn = rsqrtf(gx * gx + gy * gy + gz * gz);
        float x = gx * dn, y = gy * dn, z = gz * dn;
        float xx = x * x, yy = y * y, zz = z * z;
        float xy = x * y, yz = y * z, xz = x * z;

        float basis[16];
        basis[0]  = 0.28209479177387814f;
        basis[1]  = -0.4886025119029199f * y;
        basis[2]  =  0.4886025119029199f * z;
        basis[3]  = -0.4886025119029199f * x;
        basis[4]  =  1.0925484305920792f * xy;
        basis[5]  = -1.0925484305920792f * yz;
        basis[6]  =  0.31539156525252005f * (2.0f * zz - xx - yy);
        basis[7]  = -1.0925484305920792f * xz;
        basis[8]  =  0.5462742152960396f * (xx - yy);
        basis[9]  = -0.5900435899266435f * y * (3.0f * xx - yy);
        basis[10] =  2.890611442640554f * xy * z;
        basis[11] = -0.4570457994644658f * y * (4.0f * zz - xx - yy);
        basis[12] =  0.3731763325901154f * z * (2.0f * zz - 3.0f * xx - 3.0f * yy);
        basis[13] = -0.4570457994644658f * x * (4.0f * zz - xx - yy);
        basis[14] =  1.445305721320277f * z * (xx - yy);
        basis[15] = -0.5900435899266435f * x * (xx - 3.0f * yy);

        float f[48];
        {
            const float4* sh4 = (const float4*)(sh + idx * 48);
            float4* fv = (float4*)f;
            #pragma unroll
            for (int j = 0; j < 12; j++) fv[j] = sh4[j];
        }
        float colr = 0.0f, colg = 0.0f, colb = 0.0f;
        #pragma unroll
        for (int k = 0; k < 16; k++) {
            float bk = basis[k];
            colr = fmaf(bk, f[3 * k + 0], colr);
            colg = fmaf(bk, f[3 * k + 1], colg);
            colb = fmaf(bk, f[3 * k + 2], colb);
        }
        colr = fmaxf(colr + 0.5f, 0.0f);
        colg = fmaxf(colg + 0.5f, 0.0f);
        colb = fmaxf(colb + 0.5f, 0.0f);

        float4 ua = uA[t];
        float2 ub = uB[t];
        lA[r] = ua;
        lB[r] = make_float4(ub.x, ub.y, colr, colg);
        lC[r] = colb;
    }
    __syncthreads();

    // ---------------- Phase D: composite sorted survivor segment -----------
    int len = (M + SEGS - 1) / SEGS;
    int seg = __builtin_amdgcn_readfirstlane(wid);
    int ks  = seg * len;
    int ke  = min(M, ks + len);

    float fpx = x0 + (float)(lane & 7);
    float fpy = y0 + (float)(lane >> 3);

    float T = 1.0f, cr = 0.0f, cg = 0.0f, cb = 0.0f;
    for (int k = ks; k < ke; k++) {
        float4 qA = lA[k];      // broadcast LDS reads (wave-uniform addr)
        float4 qB = lB[k];
        float  qc = lC[k];
        float dx = fpx - qA.x;
        float dy = fpy - qA.y;
        float pw = fmaf(dx, fmaf(qA.z, dx, qA.w * dy), qB.x * (dy * dy));
        float al = qB.y * __expf(pw);
        al = fminf(al, 0.99f);
        bool ok = (pw <= 0.0f) && (al >= (1.0f / 255.0f));
        al = ok ? al : 0.0f;
        float w = al * T;
        cr = fmaf(w, qB.z, cr);
        cg = fmaf(w, qB.w, cg);
        cb = fmaf(w, qc, cb);
        T = fmaf(-al, T, T);
    }

    red[seg * 64 + lane] = make_float4(cr, cg, cb, T);
    __syncthreads();

    // ---------------- Phase E: ordered combine + store ---------------------
    if (t < 64) {
        float Tt = 1.0f, r = 0.0f, g = 0.0f, b = 0.0f;
        #pragma unroll
        for (int s = 0; s < SEGS; s++) {
            float4 v = red[s * 64 + t];
            r = fmaf(Tt, v.x, r);
            g = fmaf(Tt, v.y, g);
            b = fmaf(Tt, v.z, b);
            Tt *= v.w;
        }
        int pix = (by * 8 + (t >> 3)) * IMW + bx * 8 + (t & 7);
        out[0 * NPIX + pix] = r + Tt * bg[0];
        out[1 * NPIX + pix] = g + Tt * bg[1];
        out[2 * NPIX + pix] = b + Tt * bg[2];
    }
}

// ---------------------------------------------------------------------------
extern "C" void kernel_launch(void* const* d_in, const int* in_sizes, int n_in,
                              void* d_out, int out_size, void* d_ws, size_t ws_size,
                              hipStream_t stream)
{
    (void)in_sizes; (void)n_in; (void)out_size; (void)d_ws; (void)ws_size;

    const float* means   = (const float*)d_in[0];
    const float* sh      = (const float*)d_in[1];
    const float* opac    = (const float*)d_in[2];
    const float* scales  = (const float*)d_in[3];
    const float* rots    = (const float*)d_in[4];
    const float* campos  = (const float*)d_in[5];
    const float* camrot  = (const float*)d_in[6];
    const float* thf     = (const float*)d_in[7];
    const float* bg      = (const float*)d_in[8];
    const float* nearfar = (const float*)d_in[9];

    k_fused<<<256, 1024, 0, stream>>>(means, sh, opac, scales, rots, campos,
                                      camrot, thf, nearfar, bg, (float*)d_out);
}